// Round 1
// baseline (151.847 us; speedup 1.0000x reference)
//
#include <hip/hip_runtime.h>
#include <stdint.h>

#define B_ 2
#define S_ 2048
#define E_ 1024
#define H_ 16
#define HD_ 64
#define N_ (B_*S_)
#define BH_ (B_*H_)
#define GAMMA 0.01f

typedef __attribute__((ext_vector_type(8))) short bf16x8;
typedef __attribute__((ext_vector_type(4))) float f32x4;
typedef unsigned short u16;
typedef unsigned int u32;

// byte-level XOR swizzle within a 128B row: kills stride-128 bank conflicts,
// preserves 16B-chunk contiguity (reads/writes at 16B granularity relocate whole chunks)
#define SWZ(row, kb) ((kb) ^ (((row)&7)<<4))

__device__ __forceinline__ u16 f2bf(float f){
  union { float f; u32 u; } v; v.f = f;
  return (u16)((v.u + 0x7FFFu + ((v.u>>16)&1u)) >> 16);
}

__device__ __forceinline__ uint4 pack8(float4 a, float4 b){
  uint4 r;
  r.x = (u32)f2bf(a.x) | ((u32)f2bf(a.y)<<16);
  r.y = (u32)f2bf(a.z) | ((u32)f2bf(a.w)<<16);
  r.z = (u32)f2bf(b.x) | ((u32)f2bf(b.y)<<16);
  r.w = (u32)f2bf(b.z) | ((u32)f2bf(b.w)<<16);
  return r;
}

__device__ __forceinline__ bf16x8 ldfrag(const unsigned char* base, int row, int kbyte){
  return *reinterpret_cast<const bf16x8*>(base + row*128 + SWZ(row, kbyte));
}

// ---------------- K0: convert Wo, Wsq fp32 -> bf16 ----------------
__global__ __launch_bounds__(256) void k_cvt(const float* __restrict__ Wo, const float* __restrict__ Wsq,
                                             u16* __restrict__ wo16, u16* __restrict__ wsq16)
{
  int gid = blockIdx.x*256 + threadIdx.x;      // 0 .. 524287
  int n4 = (E_*E_)/4;                          // 262144
  const float4* src; ushort4* dst; int i;
  if (gid < n4){ src = (const float4*)Wo;  dst = (ushort4*)wo16;  i = gid; }
  else         { src = (const float4*)Wsq; dst = (ushort4*)wsq16; i = gid - n4; }
  float4 v = src[i];
  ushort4 p; p.x = f2bf(v.x); p.y = f2bf(v.y); p.z = f2bf(v.z); p.w = f2bf(v.w);
  dst[i] = p;
}

// ---------------- K1: per-head QKV projection + xnorm(v), V transposed ----------------
__device__ __forceinline__ void proj_mfma(const unsigned char* X, const unsigned char* W,
                                          int wid, int l15, int g4, f32x4 acc[4])
{
  f32x4 z = {0.f,0.f,0.f,0.f};
  acc[0]=z; acc[1]=z; acc[2]=z; acc[3]=z;
  #pragma unroll
  for (int kk=0;kk<2;++kk){
    int kbyte = kk*64 + g4*16;
    bf16x8 a = ldfrag(X, wid*16 + l15, kbyte);
    #pragma unroll
    for (int t=0;t<4;++t){
      bf16x8 w = ldfrag(W, t*16 + l15, kbyte);
      acc[t] = __builtin_amdgcn_mfma_f32_16x16x32_bf16(a, w, acc[t], 0, 0, 0);
    }
  }
}

__global__ __launch_bounds__(256) void k_proj(
    const float* __restrict__ qin, const float* __restrict__ kin, const float* __restrict__ vin,
    const float* __restrict__ Wq, const float* __restrict__ Wk, const float* __restrict__ Wv,
    u16* __restrict__ qp, u16* __restrict__ kp, u16* __restrict__ vnT)
{
  __shared__ alignas(16) unsigned char sm[57344];
  const int XQ=0, XK=8192, XV=16384, WQS=24576, WKS=32768, WVS=40960, VT=49152;
  int tid = threadIdx.x, lane = tid&63, wid = tid>>6;
  int l15 = lane&15, g4 = lane>>4;
  int tb = blockIdx.x*64;
  int h  = blockIdx.y;
  int b  = tb >> 11;
  int sbase = tb & 2047;
  int bh = b*H_ + h;

  { // stage X tiles (64 tok x 64 dims of head h) and W tiles, fp32->bf16, swizzled
    int rl = tid>>2;
    int d0 = (tid&3)*16;
    const float* xs[3] = { qin, kin, vin };
    const float* wsrc[3] = { Wq, Wk, Wv };
    const int xoff[3] = {XQ,XK,XV}, woff[3] = {WQS,WKS,WVS};
    #pragma unroll
    for (int m3=0;m3<3;++m3){
      const float4* gx = reinterpret_cast<const float4*>(xs[m3] + (size_t)(tb+rl)*E_ + h*HD_ + d0);
      float4 a=gx[0], bb=gx[1], c=gx[2], d=gx[3];
      *(uint4*)(sm + xoff[m3] + rl*128 + SWZ(rl, d0*2))    = pack8(a,bb);
      *(uint4*)(sm + xoff[m3] + rl*128 + SWZ(rl, d0*2+16)) = pack8(c,d);
      const float4* gw = reinterpret_cast<const float4*>(wsrc[m3] + rl*64 + d0);
      float4 e=gw[0], f=gw[1], g2=gw[2], h2=gw[3];
      *(uint4*)(sm + woff[m3] + rl*128 + SWZ(rl, d0*2))    = pack8(e,f);
      *(uint4*)(sm + woff[m3] + rl*128 + SWZ(rl, d0*2+16)) = pack8(g2,h2);
    }
  }
  __syncthreads();

  f32x4 acc[4];
  // Q projection -> qp[bh][s][d]
  proj_mfma(sm+XQ, sm+WQS, wid, l15, g4, acc);
  #pragma unroll
  for (int t=0;t<4;++t)
    #pragma unroll
    for (int r=0;r<4;++r){
      int tokl = wid*16 + g4*4 + r;
      qp[((size_t)bh*S_ + sbase + tokl)*HD_ + t*16 + l15] = f2bf(acc[t][r]);
    }
  // K projection -> kp[bh][s][d]
  proj_mfma(sm+XK, sm+WKS, wid, l15, g4, acc);
  #pragma unroll
  for (int t=0;t<4;++t)
    #pragma unroll
    for (int r=0;r<4;++r){
      int tokl = wid*16 + g4*4 + r;
      kp[((size_t)bh*S_ + sbase + tokl)*HD_ + t*16 + l15] = f2bf(acc[t][r]);
    }
  // V projection + xnorm over head dim -> LDS transpose -> vnT[bh][d][s]
  proj_mfma(sm+XV, sm+WVS, wid, l15, g4, acc);
  {
    float p4r[4] = {0.f,0.f,0.f,0.f};
    #pragma unroll
    for (int t=0;t<4;++t)
      #pragma unroll
      for (int r=0;r<4;++r){ float e = acc[t][r]; float e2 = e*e; p4r[r] += e2*e2; }
    #pragma unroll
    for (int r=0;r<4;++r){
      float p = p4r[r];
      p += __shfl_xor(p,1); p += __shfl_xor(p,2); p += __shfl_xor(p,4); p += __shfl_xor(p,8);
      p4r[r] = GAMMA / sqrtf(sqrtf(p));
    }
    #pragma unroll
    for (int t=0;t<4;++t)
      #pragma unroll
      for (int r=0;r<4;++r){
        int tokl = wid*16 + g4*4 + r;
        int dd = t*16 + l15;
        *(u16*)(sm + VT + dd*128 + SWZ(dd, tokl*2)) = f2bf(acc[t][r] * p4r[r]);
      }
  }
  __syncthreads();
  { // coalesced write of transposed vn
    int dd = tid>>2; int c2 = tid&3;
    size_t gbase = ((size_t)bh*HD_ + dd)*S_ + sbase + c2*16;
    uint4 v0 = *(const uint4*)(sm + VT + dd*128 + SWZ(dd, c2*32));
    uint4 v1 = *(const uint4*)(sm + VT + dd*128 + SWZ(dd, c2*32+16));
    *(uint4*)(vnT + gbase)     = v0;
    *(uint4*)(vnT + gbase + 8) = v1;
  }
}

// ---------------- K2: flash attention with L4-norm scaling ----------------
__global__ __launch_bounds__(256) void k_attn(
    const u16* __restrict__ qp, const u16* __restrict__ kp,
    const u16* __restrict__ vnT, u16* __restrict__ ao)
{
  __shared__ alignas(16) unsigned char sm[32768];
  const int KS=0, VTS=8192, ES=16384;
  int tid = threadIdx.x, lane = tid&63, wid = tid>>6;
  int l15 = lane&15, g4 = lane>>4;
  int qb = blockIdx.x*128;
  int bh = blockIdx.y;
  int b = bh >> 4, h = bh & 15;
  const u16* Kb = kp  + (size_t)bh*S_*HD_;
  const u16* Vb = vnT + (size_t)bh*HD_*S_;
  const u16* Qb = qp  + (size_t)bh*S_*HD_;

  // Q fragments in registers for the whole K loop (wave owns 32 q-rows)
  bf16x8 qf[2][2];
  #pragma unroll
  for (int m=0;m<2;++m)
    #pragma unroll
    for (int kk=0;kk<2;++kk)
      qf[m][kk] = *reinterpret_cast<const bf16x8*>(Qb + (size_t)(qb + wid*32 + m*16 + l15)*HD_ + kk*32 + g4*8);

  f32x4 z = {0.f,0.f,0.f,0.f};
  f32x4 oacc[2][4];
  float p4[2][4];
  #pragma unroll
  for (int m=0;m<2;++m)
    #pragma unroll
    for (int t=0;t<4;++t){ oacc[m][t] = z; p4[m][t] = 0.f; }

  int srow = tid>>2, scb = tid&3;
  unsigned char* es = sm + ES + wid*4096;

  for (int kt=0; kt<S_/64; ++kt){
    int kb = kt*64;
    { // stage K tile [64 keys][64 d] and Vt tile [64 d][64 keys], swizzled
      const uint4* gk = reinterpret_cast<const uint4*>(Kb + (size_t)(kb+srow)*HD_);
      uint4 k0 = gk[scb], k1 = gk[scb+4];
      const uint4* gv = reinterpret_cast<const uint4*>(Vb + (size_t)srow*S_ + kb);
      uint4 v0 = gv[scb], v1 = gv[scb+4];
      *(uint4*)(sm + KS  + srow*128 + SWZ(srow, scb*16))    = k0;
      *(uint4*)(sm + KS  + srow*128 + SWZ(srow, scb*16+64)) = k1;
      *(uint4*)(sm + VTS + srow*128 + SWZ(srow, scb*16))    = v0;
      *(uint4*)(sm + VTS + srow*128 + SWZ(srow, scb*16+64)) = v1;
    }
    __syncthreads();
    // E = Q K^T  (per wave: 32 q x 64 keys)
    f32x4 eacc[2][4];
    #pragma unroll
    for (int m=0;m<2;++m)
      #pragma unroll
      for (int t=0;t<4;++t) eacc[m][t] = z;
    #pragma unroll
    for (int kk=0;kk<2;++kk){
      int kbyte = kk*64 + g4*16;
      #pragma unroll
      for (int t=0;t<4;++t){
        bf16x8 bk = ldfrag(sm+KS, t*16+l15, kbyte);
        eacc[0][t] = __builtin_amdgcn_mfma_f32_16x16x32_bf16(qf[0][kk], bk, eacc[0][t], 0,0,0);
        eacc[1][t] = __builtin_amdgcn_mfma_f32_16x16x32_bf16(qf[1][kk], bk, eacc[1][t], 0,0,0);
      }
    }
    // E^4 row partials + write E (bf16) to per-wave LDS in A-fragment-friendly layout
    #pragma unroll
    for (int m=0;m<2;++m)
      #pragma unroll
      for (int t=0;t<4;++t)
        #pragma unroll
        for (int r=0;r<4;++r){
          float e = eacc[m][t][r];
          float e2 = e*e;
          p4[m][r] += e2*e2;
          int row = m*16 + g4*4 + r;
          *(u16*)(es + row*128 + SWZ(row, (t*16+l15)*2)) = f2bf(e);
        }
    // PV: oacc += E @ Vn
    #pragma unroll
    for (int kk=0;kk<2;++kk){
      int kbyte = kk*64 + g4*16;
      bf16x8 ea0 = ldfrag(es, l15,    kbyte);
      bf16x8 ea1 = ldfrag(es, 16+l15, kbyte);
      #pragma unroll
      for (int td=0;td<4;++td){
        bf16x8 bv = ldfrag(sm+VTS, td*16+l15, kbyte);
        oacc[0][td] = __builtin_amdgcn_mfma_f32_16x16x32_bf16(ea0, bv, oacc[0][td], 0,0,0);
        oacc[1][td] = __builtin_amdgcn_mfma_f32_16x16x32_bf16(ea1, bv, oacc[1][td], 0,0,0);
      }
    }
    __syncthreads();
  }
  // finalize: reduce p4 across the 16 col-lanes, scale, store bf16 head-output
  float sc[2][4];
  #pragma unroll
  for (int m=0;m<2;++m)
    #pragma unroll
    for (int r=0;r<4;++r){
      float p = p4[m][r];
      p += __shfl_xor(p,1); p += __shfl_xor(p,2); p += __shfl_xor(p,4); p += __shfl_xor(p,8);
      sc[m][r] = GAMMA / sqrtf(sqrtf(p));
    }
  #pragma unroll
  for (int m=0;m<2;++m)
    #pragma unroll
    for (int td=0;td<4;++td)
      #pragma unroll
      for (int r=0;r<4;++r){
        int n = b*S_ + qb + wid*32 + m*16 + g4*4 + r;
        ao[(size_t)n*E_ + h*HD_ + td*16 + l15] = f2bf(oacc[m][td][r] * sc[m][r]);
      }
}

// ---------------- K3/K5: 128x128-tile bf16 GEMM (y = A @ Bw^T) with fused epilogues ----------------
// MODE 0: out = acc + bias[col] + aux[idx]                  (Wo proj + residual)
// MODE 1: out = aux[idx] * sigmoid(acc + bias[col])          (SE gate)
template<int MODE>
__global__ __launch_bounds__(256) void k_gemm(
    const u16* __restrict__ A, const u16* __restrict__ Bw,
    const float* __restrict__ bias, const float* __restrict__ aux,
    float* __restrict__ outp)
{
  __shared__ alignas(16) unsigned char sm[32768];
  const int AS=0, BS=16384;
  int tid = threadIdx.x, lane = tid&63, wid = tid>>6;
  int l15 = lane&15, g4 = lane>>4;
  int m0 = blockIdx.y*128, n0 = blockIdx.x*128;
  int wr = wid>>1, wc = wid&1;
  f32x4 z = {0.f,0.f,0.f,0.f};
  f32x4 acc[4][4];
  #pragma unroll
  for (int i=0;i<4;++i)
    #pragma unroll
    for (int j=0;j<4;++j) acc[i][j] = z;

  int srow = tid>>1, scb4 = (tid&1)*4;
  for (int kt=0; kt<E_/64; ++kt){
    int kb = kt*64;
    const uint4* ga = reinterpret_cast<const uint4*>(A  + (size_t)(m0+srow)*E_ + kb);
    const uint4* gb = reinterpret_cast<const uint4*>(Bw + (size_t)(n0+srow)*E_ + kb);
    #pragma unroll
    for (int i=0;i<4;++i){
      uint4 va = ga[scb4+i];
      *(uint4*)(sm + AS + srow*128 + SWZ(srow, (scb4+i)*16)) = va;
    }
    #pragma unroll
    for (int i=0;i<4;++i){
      uint4 vb = gb[scb4+i];
      *(uint4*)(sm + BS + srow*128 + SWZ(srow, (scb4+i)*16)) = vb;
    }
    __syncthreads();
    #pragma unroll
    for (int kk=0;kk<2;++kk){
      int kbyte = kk*64 + g4*16;
      bf16x8 af[4];
      #pragma unroll
      for (int mi=0;mi<4;++mi) af[mi] = ldfrag(sm+AS, wr*64+mi*16+l15, kbyte);
      #pragma unroll
      for (int ni=0;ni<4;++ni){
        bf16x8 bf = ldfrag(sm+BS, wc*64+ni*16+l15, kbyte);
        #pragma unroll
        for (int mi=0;mi<4;++mi)
          acc[mi][ni] = __builtin_amdgcn_mfma_f32_16x16x32_bf16(af[mi], bf, acc[mi][ni], 0,0,0);
      }
    }
    __syncthreads();
  }
  #pragma unroll
  for (int mi=0;mi<4;++mi)
    #pragma unroll
    for (int ni=0;ni<4;++ni)
      #pragma unroll
      for (int r=0;r<4;++r){
        int row = m0 + wr*64 + mi*16 + g4*4 + r;
        int col = n0 + wc*64 + ni*16 + l15;
        size_t idx = (size_t)row*E_ + col;
        float v = acc[mi][ni][r];
        if (MODE == 0){
          outp[idx] = v + bias[col] + aux[idx];
        } else {
          float zz = v + bias[col];
          float gg = 1.f/(1.f + __expf(-zz));
          outp[idx] = aux[idx] * gg;
        }
      }
}

// ---------------- K4: LayerNorm over embed dim; writes fp32 + bf16 copies ----------------
__global__ __launch_bounds__(256) void k_ln(
    const float* __restrict__ xres, const float* __restrict__ lnw, const float* __restrict__ lnb,
    float* __restrict__ x32, u16* __restrict__ x16)
{
  __shared__ float red[8];
  __shared__ float stats[2];
  int row = blockIdx.x, tid = threadIdx.x;
  float4 x = reinterpret_cast<const float4*>(xres + (size_t)row*E_)[tid];
  float s  = x.x + x.y + x.z + x.w;
  float s2 = x.x*x.x + x.y*x.y + x.z*x.z + x.w*x.w;
  #pragma unroll
  for (int m=1;m<64;m<<=1){ s += __shfl_xor(s,m); s2 += __shfl_xor(s2,m); }
  if ((tid&63)==0){ red[tid>>6] = s; red[4+(tid>>6)] = s2; }
  __syncthreads();
  if (tid==0){
    float ts  = red[0]+red[1]+red[2]+red[3];
    float ts2 = red[4]+red[5]+red[6]+red[7];
    float mu  = ts * (1.f/E_);
    float var = ts2 * (1.f/E_) - mu*mu;
    stats[0] = mu; stats[1] = rsqrtf(var + 1e-5f);
  }
  __syncthreads();
  float mu = stats[0], rstd = stats[1];
  float4 w  = reinterpret_cast<const float4*>(lnw)[tid];
  float4 bb = reinterpret_cast<const float4*>(lnb)[tid];
  float4 y;
  y.x = (x.x-mu)*rstd*w.x + bb.x;
  y.y = (x.y-mu)*rstd*w.y + bb.y;
  y.z = (x.z-mu)*rstd*w.z + bb.z;
  y.w = (x.w-mu)*rstd*w.w + bb.w;
  reinterpret_cast<float4*>(x32 + (size_t)row*E_)[tid] = y;
  ushort4 p; p.x = f2bf(y.x); p.y = f2bf(y.y); p.z = f2bf(y.z); p.w = f2bf(y.w);
  reinterpret_cast<ushort4*>(x16 + (size_t)row*E_)[tid] = p;
}

// ---------------- host launch ----------------
extern "C" void kernel_launch(void* const* d_in, const int* in_sizes, int n_in,
                              void* d_out, int out_size, void* d_ws, size_t ws_size,
                              hipStream_t stream)
{
  const float* value = (const float*)d_in[0];
  const float* key   = (const float*)d_in[1];
  const float* query = (const float*)d_in[2];
  const float* Wq    = (const float*)d_in[3];
  const float* Wk    = (const float*)d_in[4];
  const float* Wv    = (const float*)d_in[5];
  const float* Wo    = (const float*)d_in[6];
  const float* bo    = (const float*)d_in[7];
  const float* lnw   = (const float*)d_in[8];
  const float* lnb   = (const float*)d_in[9];
  const float* Wsq   = (const float*)d_in[10];
  const float* bsq   = (const float*)d_in[11];
  float* out = (float*)d_out;

  char* ws = (char*)d_ws;
  const size_t MB = 1ull<<20;
  // lifetime-overlapped layout (52 MB total):
  u16*   qp    = (u16*)  (ws + 0*MB);    // K1->K2 ; later reused by x16
  u16*   kp    = (u16*)  (ws + 8*MB);    // K1->K2 ; later reused by xres
  u16*   vnT   = (u16*)  (ws + 16*MB);   // K1->K2 ; later reused by xres
  u16*   ao    = (u16*)  (ws + 24*MB);   // K2->K3
  float* xres  = (float*)(ws + 8*MB);    // K3->K4 (16 MB, over kp+vnT)
  u16*   x16   = (u16*)  (ws + 0*MB);    // K4->K5 (over qp)
  float* x32   = (float*)(ws + 32*MB);   // K4->K5
  u16*   wo16  = (u16*)  (ws + 48*MB);
  u16*   wsq16 = (u16*)  (ws + 50*MB);

  k_cvt <<<2048, 256, 0, stream>>>(Wo, Wsq, wo16, wsq16);
  k_proj<<<dim3(N_/64, H_), 256, 0, stream>>>(query, key, value, Wq, Wk, Wv, qp, kp, vnT);
  k_attn<<<dim3(S_/128, BH_), 256, 0, stream>>>(qp, kp, vnT, ao);
  k_gemm<0><<<dim3(E_/128, N_/128), 256, 0, stream>>>(ao, wo16, bo, query, xres);
  k_ln  <<<N_, 256, 0, stream>>>(xres, lnw, lnb, x32, x16);
  k_gemm<1><<<dim3(E_/128, N_/128), 256, 0, stream>>>(x16, wsq16, bsq, x32, out);
}

// Round 2
// 142.281 us; speedup vs baseline: 1.0672x; 1.0672x over previous
//
#include <hip/hip_runtime.h>
#include <stdint.h>

#define B_ 2
#define S_ 2048
#define E_ 1024
#define H_ 16
#define HD_ 64
#define N_ (B_*S_)
#define BH_ (B_*H_)
#define GAMMA 0.01f

typedef __attribute__((ext_vector_type(8))) short bf16x8;
typedef __attribute__((ext_vector_type(4))) float f32x4;
typedef __attribute__((ext_vector_type(16))) float f32x16;
typedef __attribute__((ext_vector_type(4))) unsigned int u32x4;
typedef unsigned short u16;
typedef unsigned int u32;

// byte-level XOR swizzle within a 128B row: kills stride-128 bank conflicts,
// preserves 16B-chunk contiguity
#define SWZ(row, kb) ((kb) ^ (((row)&7)<<4))

__device__ __forceinline__ u16 f2bf(float f){
  union { float f; u32 u; } v; v.f = f;
  return (u16)((v.u + 0x7FFFu + ((v.u>>16)&1u)) >> 16);
}

__device__ __forceinline__ u32 cvt_pk_bf16(float lo, float hi){
  u32 r; asm("v_cvt_pk_bf16_f32 %0, %1, %2" : "=v"(r) : "v"(lo), "v"(hi)); return r;
}

__device__ __forceinline__ uint4 pack8(float4 a, float4 b){
  uint4 r;
  r.x = (u32)f2bf(a.x) | ((u32)f2bf(a.y)<<16);
  r.y = (u32)f2bf(a.z) | ((u32)f2bf(a.w)<<16);
  r.z = (u32)f2bf(b.x) | ((u32)f2bf(b.y)<<16);
  r.w = (u32)f2bf(b.z) | ((u32)f2bf(b.w)<<16);
  return r;
}

__device__ __forceinline__ bf16x8 ldfrag(const unsigned char* base, int row, int kbyte){
  return *reinterpret_cast<const bf16x8*>(base + row*128 + SWZ(row, kbyte));
}

// ---------------- K0: convert Wo, Wsq fp32 -> bf16 ----------------
__global__ __launch_bounds__(256) void k_cvt(const float* __restrict__ Wo, const float* __restrict__ Wsq,
                                             u16* __restrict__ wo16, u16* __restrict__ wsq16)
{
  int gid = blockIdx.x*256 + threadIdx.x;
  int n4 = (E_*E_)/4;
  const float4* src; ushort4* dst; int i;
  if (gid < n4){ src = (const float4*)Wo;  dst = (ushort4*)wo16;  i = gid; }
  else         { src = (const float4*)Wsq; dst = (ushort4*)wsq16; i = gid - n4; }
  float4 v = src[i];
  ushort4 p; p.x = f2bf(v.x); p.y = f2bf(v.y); p.z = f2bf(v.z); p.w = f2bf(v.w);
  dst[i] = p;
}

// ---------------- K1: per-head QKV projection + xnorm(v), V transposed ----------------
__device__ __forceinline__ void proj_mfma(const unsigned char* X, const unsigned char* W,
                                          int wid, int l15, int g4, f32x4 acc[4])
{
  f32x4 z = {0.f,0.f,0.f,0.f};
  acc[0]=z; acc[1]=z; acc[2]=z; acc[3]=z;
  #pragma unroll
  for (int kk=0;kk<2;++kk){
    int kbyte = kk*64 + g4*16;
    bf16x8 a = ldfrag(X, wid*16 + l15, kbyte);
    #pragma unroll
    for (int t=0;t<4;++t){
      bf16x8 w = ldfrag(W, t*16 + l15, kbyte);
      acc[t] = __builtin_amdgcn_mfma_f32_16x16x32_bf16(a, w, acc[t], 0, 0, 0);
    }
  }
}

__global__ __launch_bounds__(256) void k_proj(
    const float* __restrict__ qin, const float* __restrict__ kin, const float* __restrict__ vin,
    const float* __restrict__ Wq, const float* __restrict__ Wk, const float* __restrict__ Wv,
    u16* __restrict__ qp, u16* __restrict__ kp, u16* __restrict__ vnT)
{
  __shared__ alignas(16) unsigned char sm[57344];
  const int XQ=0, XK=8192, XV=16384, WQS=24576, WKS=32768, WVS=40960, VT=49152;
  int tid = threadIdx.x, lane = tid&63, wid = tid>>6;
  int l15 = lane&15, g4 = lane>>4;
  int tb = blockIdx.x*64;
  int h  = blockIdx.y;
  int b  = tb >> 11;
  int sbase = tb & 2047;
  int bh = b*H_ + h;

  {
    int rl = tid>>2;
    int d0 = (tid&3)*16;
    const float* xs[3] = { qin, kin, vin };
    const float* wsrc[3] = { Wq, Wk, Wv };
    const int xoff[3] = {XQ,XK,XV}, woff[3] = {WQS,WKS,WVS};
    #pragma unroll
    for (int m3=0;m3<3;++m3){
      const float4* gx = reinterpret_cast<const float4*>(xs[m3] + (size_t)(tb+rl)*E_ + h*HD_ + d0);
      float4 a=gx[0], bb=gx[1], c=gx[2], d=gx[3];
      *(uint4*)(sm + xoff[m3] + rl*128 + SWZ(rl, d0*2))    = pack8(a,bb);
      *(uint4*)(sm + xoff[m3] + rl*128 + SWZ(rl, d0*2+16)) = pack8(c,d);
      const float4* gw = reinterpret_cast<const float4*>(wsrc[m3] + rl*64 + d0);
      float4 e=gw[0], f=gw[1], g2=gw[2], h2=gw[3];
      *(uint4*)(sm + woff[m3] + rl*128 + SWZ(rl, d0*2))    = pack8(e,f);
      *(uint4*)(sm + woff[m3] + rl*128 + SWZ(rl, d0*2+16)) = pack8(g2,h2);
    }
  }
  __syncthreads();

  f32x4 acc[4];
  proj_mfma(sm+XQ, sm+WQS, wid, l15, g4, acc);
  #pragma unroll
  for (int t=0;t<4;++t)
    #pragma unroll
    for (int r=0;r<4;++r){
      int tokl = wid*16 + g4*4 + r;
      qp[((size_t)bh*S_ + sbase + tokl)*HD_ + t*16 + l15] = f2bf(acc[t][r]);
    }
  proj_mfma(sm+XK, sm+WKS, wid, l15, g4, acc);
  #pragma unroll
  for (int t=0;t<4;++t)
    #pragma unroll
    for (int r=0;r<4;++r){
      int tokl = wid*16 + g4*4 + r;
      kp[((size_t)bh*S_ + sbase + tokl)*HD_ + t*16 + l15] = f2bf(acc[t][r]);
    }
  proj_mfma(sm+XV, sm+WVS, wid, l15, g4, acc);
  {
    float p4r[4] = {0.f,0.f,0.f,0.f};
    #pragma unroll
    for (int t=0;t<4;++t)
      #pragma unroll
      for (int r=0;r<4;++r){ float e = acc[t][r]; float e2 = e*e; p4r[r] += e2*e2; }
    #pragma unroll
    for (int r=0;r<4;++r){
      float p = p4r[r];
      p += __shfl_xor(p,1); p += __shfl_xor(p,2); p += __shfl_xor(p,4); p += __shfl_xor(p,8);
      p4r[r] = GAMMA / sqrtf(sqrtf(p));
    }
    #pragma unroll
    for (int t=0;t<4;++t)
      #pragma unroll
      for (int r=0;r<4;++r){
        int tokl = wid*16 + g4*4 + r;
        int dd = t*16 + l15;
        *(u16*)(sm + VT + dd*128 + SWZ(dd, tokl*2)) = f2bf(acc[t][r] * p4r[r]);
      }
  }
  __syncthreads();
  {
    int dd = tid>>2; int c2 = tid&3;
    size_t gbase = ((size_t)bh*HD_ + dd)*S_ + sbase + c2*16;
    uint4 v0 = *(const uint4*)(sm + VT + dd*128 + SWZ(dd, c2*32));
    uint4 v1 = *(const uint4*)(sm + VT + dd*128 + SWZ(dd, c2*32+16));
    *(uint4*)(vnT + gbase)     = v0;
    *(uint4*)(vnT + gbase + 8) = v1;
  }
}

// ---------------- K2: flash attention, swapped-QK 32x32 MFMA, in-register E exchange ----------------
// Wave owns 32 q-rows (q = q0 + lane&31 as the MFMA column axis).
// E = mfma32(K_frag, Q_frag): lane holds E[q=l31][key=(r&3)+8*(r>>2)+4*hi] per 32-key block.
// PV A-frag built in-register: cvt_pk pairs + shfl_xor(32) half-exchange.
__global__ __launch_bounds__(256) void k_attn(
    const u16* __restrict__ qp, const u16* __restrict__ kp,
    const u16* __restrict__ vnT, u16* __restrict__ ao)
{
  __shared__ alignas(16) unsigned char sm[32768];   // 2 x (K 8KB + V 8KB)
  int tid = threadIdx.x, lane = tid&63, wv = tid>>6;
  int l31 = lane&31, hi = lane>>5;
  int qb = blockIdx.x*128;
  int bh = blockIdx.y;
  int b = bh >> 4, h = bh & 15;
  const u16* Kb = kp  + (size_t)bh*S_*HD_;
  const u16* Vb = vnT + (size_t)bh*HD_*S_;
  const u16* Qb = qp  + (size_t)bh*S_*HD_;
  int q0 = qb + wv*32;

  // Q fragments (B-operand of 32x32x16): B[col=q=l31][k=16*kk+hi*8+j]
  bf16x8 qf[4];
  #pragma unroll
  for (int kk=0;kk<4;++kk)
    qf[kk] = *reinterpret_cast<const bf16x8*>(Qb + (size_t)(q0+l31)*HD_ + kk*16 + hi*8);

  f32x16 o0 = {}, o1 = {};
  float p4 = 0.f;

  int srow = tid>>2, scb = tid&3;
  uint4 rk0, rk1, rv0, rv1;

  auto LOADT = [&](int kt){
    const uint4* gk = reinterpret_cast<const uint4*>(Kb + (size_t)(kt*64+srow)*HD_);
    rk0 = gk[scb]; rk1 = gk[scb+4];
    const uint4* gv = reinterpret_cast<const uint4*>(Vb + (size_t)srow*S_ + kt*64);
    rv0 = gv[scb]; rv1 = gv[scb+4];
  };
  auto WRITET = [&](int bsel){
    unsigned char* K_ = sm + bsel*16384;
    unsigned char* V_ = K_ + 8192;
    *(uint4*)(K_ + srow*128 + SWZ(srow, scb*16))    = rk0;
    *(uint4*)(K_ + srow*128 + SWZ(srow, scb*16+64)) = rk1;
    *(uint4*)(V_ + srow*128 + SWZ(srow, scb*16))    = rv0;
    *(uint4*)(V_ + srow*128 + SWZ(srow, scb*16+64)) = rv1;
  };

  LOADT(0); WRITET(0);
  __syncthreads();

  for (int kt=0; kt<S_/64; ++kt){
    if (kt < S_/64 - 1) LOADT(kt+1);        // async-stage split: issue early
    const unsigned char* K_ = sm + (kt&1)*16384;
    const unsigned char* V_ = K_ + 8192;

    // ---- QK^T (swapped): A = K rows, B = Q ----
    f32x16 e0 = {}, e1 = {};
    #pragma unroll
    for (int kk=0;kk<4;++kk){
      bf16x8 ka0 = ldfrag(K_, l31,    kk*32 + hi*16);
      bf16x8 ka1 = ldfrag(K_, 32+l31, kk*32 + hi*16);
      e0 = __builtin_amdgcn_mfma_f32_32x32x16_bf16(ka0, qf[kk], e0, 0,0,0);
      e1 = __builtin_amdgcn_mfma_f32_32x32x16_bf16(ka1, qf[kk], e1, 0,0,0);
    }

    // ---- p4 accumulation + pack E -> bf16 words ----
    // word w[kb2][g][i] = keys 32*kb2 + 8*g + 4*hi + {2i, 2i+1} of q-row l31
    u32 wrd[2][4][2];
    #pragma unroll
    for (int g=0; g<4; ++g)
      #pragma unroll
      for (int i=0;i<2;++i){
        float a0 = e0[4*g+2*i], b0 = e0[4*g+2*i+1];
        float a1 = e1[4*g+2*i], b1 = e1[4*g+2*i+1];
        float a02=a0*a0, b02=b0*b0, a12=a1*a1, b12=b1*b1;
        p4 += a02*a02; p4 += b02*b02; p4 += a12*a12; p4 += b12*b12;
        wrd[0][g][i] = cvt_pk_bf16(a0, b0);
        wrd[1][g][i] = cvt_pk_bf16(a1, b1);
      }

    // ---- PV: A-frag assembly via half-swap, B = V^T from LDS ----
    #pragma unroll
    for (int s=0;s<4;++s){
      const int kb2 = s>>1, sl = s&1;
      u32 send0 = hi ? wrd[kb2][2*sl][0] : wrd[kb2][2*sl+1][0];
      u32 send1 = hi ? wrd[kb2][2*sl][1] : wrd[kb2][2*sl+1][1];
      u32 r0 = (u32)__shfl_xor((int)send0, 32);
      u32 r1 = (u32)__shfl_xor((int)send1, 32);
      u32x4 fw;
      fw.x = hi ? r0 : wrd[kb2][2*sl][0];
      fw.y = hi ? r1 : wrd[kb2][2*sl][1];
      fw.z = hi ? wrd[kb2][2*sl+1][0] : r0;
      fw.w = hi ? wrd[kb2][2*sl+1][1] : r1;
      bf16x8 ef = __builtin_bit_cast(bf16x8, fw);
      bf16x8 vb0 = ldfrag(V_, l31,    s*32 + hi*16);
      bf16x8 vb1 = ldfrag(V_, 32+l31, s*32 + hi*16);
      o0 = __builtin_amdgcn_mfma_f32_32x32x16_bf16(ef, vb0, o0, 0,0,0);
      o1 = __builtin_amdgcn_mfma_f32_32x32x16_bf16(ef, vb1, o1, 0,0,0);
    }

    if (kt < S_/64 - 1) WRITET((kt+1)&1);   // write-late (vmcnt waits here, latency hidden)
    __syncthreads();
  }

  // ---- epilogue: L4-norm scale + store ----
  p4 += __shfl_xor(p4, 32);
  float sc_col = GAMMA * rsqrtf(sqrtf(p4));    // gamma * p4^{-1/4}, for q = q0 + l31
  #pragma unroll
  for (int r=0;r<16;++r){
    int qrow = (r&3) + 8*(r>>2) + 4*hi;
    float scr = __shfl(sc_col, qrow);
    size_t n = (size_t)b*S_ + qb + wv*32 + qrow;
    u16* dst = ao + n*E_ + h*HD_;
    dst[l31]    = f2bf(o0[r] * scr);
    dst[32+l31] = f2bf(o1[r] * scr);
  }
}

// ---------------- K3/K5: 128x128-tile bf16 GEMM (y = A @ Bw^T) with fused epilogues ----------------
template<int MODE>
__global__ __launch_bounds__(256) void k_gemm(
    const u16* __restrict__ A, const u16* __restrict__ Bw,
    const float* __restrict__ bias, const float* __restrict__ aux,
    float* __restrict__ outp)
{
  __shared__ alignas(16) unsigned char sm[32768];
  const int AS=0, BS=16384;
  int tid = threadIdx.x, lane = tid&63, wid = tid>>6;
  int l15 = lane&15, g4 = lane>>4;
  int m0 = blockIdx.y*128, n0 = blockIdx.x*128;
  int wr = wid>>1, wc = wid&1;
  f32x4 z = {0.f,0.f,0.f,0.f};
  f32x4 acc[4][4];
  #pragma unroll
  for (int i=0;i<4;++i)
    #pragma unroll
    for (int j=0;j<4;++j) acc[i][j] = z;

  int srow = tid>>1, scb4 = (tid&1)*4;
  for (int kt=0; kt<E_/64; ++kt){
    int kb = kt*64;
    const uint4* ga = reinterpret_cast<const uint4*>(A  + (size_t)(m0+srow)*E_ + kb);
    const uint4* gb = reinterpret_cast<const uint4*>(Bw + (size_t)(n0+srow)*E_ + kb);
    #pragma unroll
    for (int i=0;i<4;++i){
      uint4 va = ga[scb4+i];
      *(uint4*)(sm + AS + srow*128 + SWZ(srow, (scb4+i)*16)) = va;
    }
    #pragma unroll
    for (int i=0;i<4;++i){
      uint4 vb = gb[scb4+i];
      *(uint4*)(sm + BS + srow*128 + SWZ(srow, (scb4+i)*16)) = vb;
    }
    __syncthreads();
    #pragma unroll
    for (int kk=0;kk<2;++kk){
      int kbyte = kk*64 + g4*16;
      bf16x8 af[4];
      #pragma unroll
      for (int mi=0;mi<4;++mi) af[mi] = ldfrag(sm+AS, wr*64+mi*16+l15, kbyte);
      #pragma unroll
      for (int ni=0;ni<4;++ni){
        bf16x8 bf = ldfrag(sm+BS, wc*64+ni*16+l15, kbyte);
        #pragma unroll
        for (int mi=0;mi<4;++mi)
          acc[mi][ni] = __builtin_amdgcn_mfma_f32_16x16x32_bf16(af[mi], bf, acc[mi][ni], 0,0,0);
      }
    }
    __syncthreads();
  }
  #pragma unroll
  for (int mi=0;mi<4;++mi)
    #pragma unroll
    for (int ni=0;ni<4;++ni)
      #pragma unroll
      for (int r=0;r<4;++r){
        int row = m0 + wr*64 + mi*16 + g4*4 + r;
        int col = n0 + wc*64 + ni*16 + l15;
        size_t idx = (size_t)row*E_ + col;
        float v = acc[mi][ni][r];
        if (MODE == 0){
          outp[idx] = v + bias[col] + aux[idx];
        } else {
          float zz = v + bias[col];
          float gg = 1.f/(1.f + __expf(-zz));
          outp[idx] = aux[idx] * gg;
        }
      }
}

// ---------------- K4: LayerNorm over embed dim; writes fp32 + bf16 copies ----------------
__global__ __launch_bounds__(256) void k_ln(
    const float* __restrict__ xres, const float* __restrict__ lnw, const float* __restrict__ lnb,
    float* __restrict__ x32, u16* __restrict__ x16)
{
  __shared__ float red[8];
  __shared__ float stats[2];
  int row = blockIdx.x, tid = threadIdx.x;
  float4 x = reinterpret_cast<const float4*>(xres + (size_t)row*E_)[tid];
  float s  = x.x + x.y + x.z + x.w;
  float s2 = x.x*x.x + x.y*x.y + x.z*x.z + x.w*x.w;
  #pragma unroll
  for (int m=1;m<64;m<<=1){ s += __shfl_xor(s,m); s2 += __shfl_xor(s2,m); }
  if ((tid&63)==0){ red[tid>>6] = s; red[4+(tid>>6)] = s2; }
  __syncthreads();
  if (tid==0){
    float ts  = red[0]+red[1]+red[2]+red[3];
    float ts2 = red[4]+red[5]+red[6]+red[7];
    float mu  = ts * (1.f/E_);
    float var = ts2 * (1.f/E_) - mu*mu;
    stats[0] = mu; stats[1] = rsqrtf(var + 1e-5f);
  }
  __syncthreads();
  float mu = stats[0], rstd = stats[1];
  float4 w  = reinterpret_cast<const float4*>(lnw)[tid];
  float4 bb = reinterpret_cast<const float4*>(lnb)[tid];
  float4 y;
  y.x = (x.x-mu)*rstd*w.x + bb.x;
  y.y = (x.y-mu)*rstd*w.y + bb.y;
  y.z = (x.z-mu)*rstd*w.z + bb.z;
  y.w = (x.w-mu)*rstd*w.w + bb.w;
  reinterpret_cast<float4*>(x32 + (size_t)row*E_)[tid] = y;
  ushort4 p; p.x = f2bf(y.x); p.y = f2bf(y.y); p.z = f2bf(y.z); p.w = f2bf(y.w);
  reinterpret_cast<ushort4*>(x16 + (size_t)row*E_)[tid] = p;
}

// ---------------- host launch ----------------
extern "C" void kernel_launch(void* const* d_in, const int* in_sizes, int n_in,
                              void* d_out, int out_size, void* d_ws, size_t ws_size,
                              hipStream_t stream)
{
  const float* value = (const float*)d_in[0];
  const float* key   = (const float*)d_in[1];
  const float* query = (const float*)d_in[2];
  const float* Wq    = (const float*)d_in[3];
  const float* Wk    = (const float*)d_in[4];
  const float* Wv    = (const float*)d_in[5];
  const float* Wo    = (const float*)d_in[6];
  const float* bo    = (const float*)d_in[7];
  const float* lnw   = (const float*)d_in[8];
  const float* lnb   = (const float*)d_in[9];
  const float* Wsq   = (const float*)d_in[10];
  const float* bsq   = (const float*)d_in[11];
  float* out = (float*)d_out;

  char* ws = (char*)d_ws;
  const size_t MB = 1ull<<20;
  u16*   qp    = (u16*)  (ws + 0*MB);
  u16*   kp    = (u16*)  (ws + 8*MB);
  u16*   vnT   = (u16*)  (ws + 16*MB);
  u16*   ao    = (u16*)  (ws + 24*MB);
  float* xres  = (float*)(ws + 8*MB);
  u16*   x16   = (u16*)  (ws + 0*MB);
  float* x32   = (float*)(ws + 32*MB);
  u16*   wo16  = (u16*)  (ws + 48*MB);
  u16*   wsq16 = (u16*)  (ws + 50*MB);

  k_cvt <<<2048, 256, 0, stream>>>(Wo, Wsq, wo16, wsq16);
  k_proj<<<dim3(N_/64, H_), 256, 0, stream>>>(query, key, value, Wq, Wk, Wv, qp, kp, vnT);
  k_attn<<<dim3(S_/128, BH_), 256, 0, stream>>>(qp, kp, vnT, ao);
  k_gemm<0><<<dim3(E_/128, N_/128), 256, 0, stream>>>(ao, wo16, bo, query, xres);
  k_ln  <<<N_, 256, 0, stream>>>(xres, lnw, lnb, x32, x16);
  k_gemm<1><<<dim3(E_/128, N_/128), 256, 0, stream>>>(x16, wsq16, bsq, x32, out);
}